// Round 4
// baseline (114.593 us; speedup 1.0000x reference)
//
#include <hip/hip_runtime.h>
#include <math.h>

#define B 64
#define N 4096
#define K 819            // int(4096 * 0.2)
#define EPSF 1e-8f
#define TRADE_LAMBDA 0.25f

#define PAIR_IT 4        // i tiles of 256
#define PAIR_JZ 8        // j chunks of 103
#define PAIR_NBLK (B * PAIR_IT * PAIR_JZ)

// ws layout (floats):
//   s_top[B][K], w_top[B][K] (sqrt w), s_bot[B][K], w_bot[B][K],
//   rank_num[B], sum_swt[B], sum_swb[B], trade_num[B], trade_wsum[B],
//   p_sum[B], done_counter (int)
#define OFF_STOP 0
#define OFF_WTOP (B*K)
#define OFF_SBOT (2*B*K)
#define OFF_WBOT (3*B*K)
#define OFF_RNUM (4*B*K)
#define OFF_SWT  (4*B*K + B)
#define OFF_SWB  (4*B*K + 2*B)
#define OFF_TNUM (4*B*K + 3*B)
#define OFF_TWS  (4*B*K + 4*B)
#define OFF_PSUM (4*B*K + 5*B)
#define OFF_DONE (4*B*K + 6*B)

__device__ __forceinline__ unsigned f2key(float f) {
    unsigned u = __float_as_uint(f);
    return (u & 0x80000000u) ? ~u : (u | 0x80000000u);
}

__device__ __forceinline__ float softplusf(float x) {
    float ax = fabsf(x);
    return fmaxf(x, 0.f) + __logf(1.f + __expf(-ax));
}

// Scan helpers: called by wave 0 (scan_top, lanes 0..63) / wave 1 (scan_bot).
// h = 256-bin histogram; finds bin containing the rem-th largest/smallest.
// found[0]=bin, found[1]=count strictly outside (above for top, below for bot).
__device__ __forceinline__ void scan_top(const int* h, int rem, int* found) {
    const int t = threadIdx.x;           // 0..63
    const int base = t * 4;
    int c0 = h[base], c1 = h[base+1], c2 = h[base+2], c3 = h[base+3];
    int lane_sum = c0 + c1 + c2 + c3;
    int s = lane_sum;
    #pragma unroll
    for (int o = 1; o < 64; o <<= 1) {
        int v = __shfl_down(s, o, 64);
        if (t + o < 64) s += v;
    }
    int above = s - lane_sum;            // keys in bins > base+3
    int se3 = above;
    int se2 = se3 + c3;
    int se1 = se2 + c2;
    int se0 = se1 + c1;
    if (se0 < rem && rem <= se0 + c0) { found[0] = base + 0; found[1] = se0; }
    if (se1 < rem && rem <= se1 + c1) { found[0] = base + 1; found[1] = se1; }
    if (se2 < rem && rem <= se2 + c2) { found[0] = base + 2; found[1] = se2; }
    if (se3 < rem && rem <= se3 + c3) { found[0] = base + 3; found[1] = se3; }
}

__device__ __forceinline__ void scan_bot(const int* h, int rem, int* found) {
    const int l = threadIdx.x - 64;      // 0..63 within wave 1
    const int base = l * 4;
    int c0 = h[base], c1 = h[base+1], c2 = h[base+2], c3 = h[base+3];
    int lane_sum = c0 + c1 + c2 + c3;
    int s = lane_sum;
    #pragma unroll
    for (int o = 1; o < 64; o <<= 1) {
        int v = __shfl_up(s, o, 64);
        if (l - o >= 0) s += v;
    }
    int below = s - lane_sum;            // keys in bins < base
    int pe0 = below;
    int pe1 = pe0 + c0;
    int pe2 = pe1 + c1;
    int pe3 = pe2 + c2;
    if (pe0 < rem && rem <= pe0 + c0) { found[0] = base + 0; found[1] = pe0; }
    if (pe1 < rem && rem <= pe1 + c1) { found[0] = base + 1; found[1] = pe1; }
    if (pe2 < rem && rem <= pe2 + c2) { found[0] = base + 2; found[1] = pe2; }
    if (pe3 < rem && rem <= pe3 + c3) { found[0] = base + 3; found[1] = pe3; }
}

// Heterogeneous grid of 128 blocks x 1024 threads:
//   blocks 0..63   : radix-select top-K / bottom-K of y_rank row b, gather
//                    scores & sqrt-weights into ws (keys+payload in registers)
//   blocks 64..127 : trade-loss (BCE) row sums for row b-64; b==0 also zeroes
//                    the done-counter used by k_pair_final
__global__ __launch_bounds__(1024) void k_select_trade(
    const float* __restrict__ scores, const float* __restrict__ p_trade,
    const float* __restrict__ y_rank, const float* __restrict__ y_trade,
    const float* __restrict__ weights, const float* __restrict__ mask,
    float* __restrict__ ws)
{
    __shared__ int histw[16 * 256];   // per-wave slices (pass 0 only), 16 KB
    __shared__ int tot[256];
    __shared__ int hist_t[256];
    __shared__ int hist_b[256];
    __shared__ int found_t[2];        // [bin, excl_count]
    __shared__ int found_b[2];
    __shared__ float red[48];
    __shared__ int cnts[8];

    const int tid = threadIdx.x;

    if (blockIdx.x >= 64) {
        // ================= trade role =================
        const int b = blockIdx.x - 64;
        const float* wt = weights + b * N;
        const float* pt = p_trade + b * N;
        const float* yt = y_trade + b * N;
        const float* mk = mask    + b * N;
        float s_wsum = 0.f, s_tnum = 0.f, s_ps = 0.f;
        #pragma unroll
        for (int c = 0; c < 4; c++) {
            int i = tid + c * 1024;
            float p = pt[i], ytr = yt[i], w = wt[i], m = mk[i];
            float mw = w * m;
            float bce = -(ytr * __logf(p) + (1.f - ytr) * __logf(1.f - p));
            s_wsum += mw;
            s_tnum = fmaf(bce, mw, s_tnum);
            s_ps += p;
        }
        #pragma unroll
        for (int o = 32; o > 0; o >>= 1) {
            s_wsum += __shfl_down(s_wsum, o, 64);
            s_tnum += __shfl_down(s_tnum, o, 64);
            s_ps   += __shfl_down(s_ps,   o, 64);
        }
        int wv = tid >> 6;
        if ((tid & 63) == 0) { red[wv] = s_wsum; red[16 + wv] = s_tnum; red[32 + wv] = s_ps; }
        __syncthreads();
        if (tid == 0) {
            float a = 0.f, bb = 0.f, c = 0.f;
            for (int w = 0; w < 16; w++) { a += red[w]; bb += red[16 + w]; c += red[32 + w]; }
            ws[OFF_TWS  + b] = a;
            ws[OFF_TNUM + b] = bb;
            ws[OFF_PSUM + b] = c;
            ws[OFF_RNUM + b] = 0.f;   // zero accumulator for k_pair_final
            if (b == 0) ((int*)ws)[OFF_DONE] = 0;
        }
        return;
    }

    // ================= select role =================
    const int b = blockIdx.x;
    const float* yr = y_rank  + b * N;
    const float* sc = scores  + b * N;
    const float* wt = weights + b * N;

    // ---- pass 1: keys + payload into registers (coalesced) ----
    unsigned mykeys[4];
    float mysc[4], mysw[4];
    #pragma unroll
    for (int c = 0; c < 4; c++) {
        int i = tid + c * 1024;
        mykeys[c] = f2key(yr[i]);
        mysc[c] = sc[i];
        mysw[c] = sqrtf(wt[i]);
    }

    // ---- radix pass 0 (MSB byte): ONE histogram (top/bot candidate sets
    //      are identical when the prefix is empty), per-wave slices to
    //      avoid hot-bin atomic serialization on concentrated exponents ----
    for (int i = tid; i < 16 * 256; i += 1024) histw[i] = 0;
    __syncthreads();
    {
        const int slice = (tid >> 6) << 8;
        #pragma unroll
        for (int c = 0; c < 4; c++)
            atomicAdd(&histw[slice | (mykeys[c] >> 24)], 1);
    }
    __syncthreads();
    if (tid < 256) {
        int s = 0;
        #pragma unroll
        for (int w = 0; w < 16; w++) s += histw[(w << 8) | tid];
        tot[tid] = s;
    }
    __syncthreads();
    if (tid < 64)       scan_top(tot, K, found_t);
    else if (tid < 128) scan_bot(tot, K, found_b);
    __syncthreads();

    unsigned pfx_t = ((unsigned)found_t[0]) << 24;
    int rem_t = K - found_t[1];
    unsigned pfx_b = ((unsigned)found_b[0]) << 24;
    int rem_b = K - found_b[1];
    unsigned msk = 0xFF000000u;

    // ---- radix passes 1..3: candidates are few & mantissa-uniform ----
    #pragma unroll
    for (int pass = 1; pass < 4; pass++) {
        const int shift = 24 - 8 * pass;
        if (tid < 256) hist_t[tid] = 0;
        else if (tid < 512) hist_b[tid - 256] = 0;
        __syncthreads();
        #pragma unroll
        for (int c = 0; c < 4; c++) {
            unsigned kk = mykeys[c];
            if ((kk & msk) == pfx_t) atomicAdd(&hist_t[(kk >> shift) & 0xFF], 1);
            if ((kk & msk) == pfx_b) atomicAdd(&hist_b[(kk >> shift) & 0xFF], 1);
        }
        __syncthreads();
        if (tid < 64)       scan_top(hist_t, rem_t, found_t);
        else if (tid < 128) scan_bot(hist_b, rem_b, found_b);
        __syncthreads();
        pfx_t |= ((unsigned)found_t[0]) << shift;
        rem_t -= found_t[1];
        pfx_b |= ((unsigned)found_b[0]) << shift;
        rem_b -= found_b[1];
        msk |= 0xFFu << shift;
    }
    const unsigned t_top = pfx_t;  // exact K-th largest key
    const unsigned t_bot = pfx_b;  // exact K-th smallest key

    if (tid < 8) cnts[tid] = 0;
    __syncthreads();

    // ---- count strict-side elements ----
    int my_gt = 0, my_lt = 0;
    #pragma unroll
    for (int c = 0; c < 4; c++) {
        unsigned kk = mykeys[c];
        my_gt += (kk > t_top);
        my_lt += (kk < t_bot);
    }
    if (my_gt) atomicAdd(&cnts[0], my_gt);
    if (my_lt) atomicAdd(&cnts[1], my_lt);
    __syncthreads();
    const int c1t = cnts[0];
    const int c1b = cnts[1];

    // ---- gather top-k / bottom-k (exact, tie-aware; payload from regs) ----
    float* s_top = ws + OFF_STOP + b * K;
    float* w_top = ws + OFF_WTOP + b * K;
    float* s_bot = ws + OFF_SBOT + b * K;
    float* w_bot = ws + OFF_WBOT + b * K;
    float swt = 0.f, swb = 0.f;
    #pragma unroll
    for (int c = 0; c < 4; c++) {
        unsigned kk = mykeys[c];
        if (kk > t_top) {
            int pos = atomicAdd(&cnts[2], 1);
            s_top[pos] = mysc[c]; w_top[pos] = mysw[c]; swt += mysw[c];
        } else if (kk == t_top) {
            int tt = atomicAdd(&cnts[3], 1);
            if (tt < K - c1t) {
                int pos = c1t + tt;
                s_top[pos] = mysc[c]; w_top[pos] = mysw[c]; swt += mysw[c];
            }
        }
        if (kk < t_bot) {
            int pos = atomicAdd(&cnts[4], 1);
            s_bot[pos] = mysc[c]; w_bot[pos] = mysw[c]; swb += mysw[c];
        } else if (kk == t_bot) {
            int tt = atomicAdd(&cnts[5], 1);
            if (tt < K - c1b) {
                int pos = c1b + tt;
                s_bot[pos] = mysc[c]; w_bot[pos] = mysw[c]; swb += mysw[c];
            }
        }
    }
    #pragma unroll
    for (int o = 32; o > 0; o >>= 1) {
        swt += __shfl_down(swt, o, 64);
        swb += __shfl_down(swb, o, 64);
    }
    __syncthreads();
    {
        int wv = tid >> 6;
        if ((tid & 63) == 0) { red[wv] = swt; red[16 + wv] = swb; }
    }
    __syncthreads();
    if (tid == 0) {
        float a = 0.f, bb = 0.f;
        for (int w = 0; w < 16; w++) { a += red[w]; bb += red[16 + w]; }
        ws[OFF_SWT + b] = a;
        ws[OFF_SWB + b] = bb;
    }
}

// Pairwise softplus reduction + fused finalize.
// grid = (B, 4 i-tiles, 8 j-chunks) = 2048 blocks, 256 thr, 8 blocks/CU
// (__launch_bounds__(256,8) => 8 waves/SIMD: latency-hiding for the
// exp->log dependent chains). Last block to finish runs the finalize.
__global__ __launch_bounds__(256, 8) void k_pair_final(
    float* __restrict__ ws, float* __restrict__ out)
{
    __shared__ __align__(16) float sb[104];
    __shared__ __align__(16) float wb[104];
    __shared__ float red2[4];
    __shared__ int lastflag;

    const int b = blockIdx.x;
    const int it = blockIdx.y;   // i tile
    const int z  = blockIdx.z;   // j chunk
    const int tid = threadIdx.x;

    const float* s_top = ws + OFF_STOP + b * K;
    const float* w_top = ws + OFF_WTOP + b * K;
    const float* s_bot = ws + OFF_SBOT + b * K;
    const float* w_bot = ws + OFF_WBOT + b * K;

    const int jbase = z * 103;
    const int jlen  = (z == 7) ? (K - 7 * 103) : 103;   // 98 for z==7

    if (tid < 104) {
        if (tid < jlen) { sb[tid] = s_bot[jbase + tid]; wb[tid] = w_bot[jbase + tid]; }
        else            { sb[tid] = 0.f;                wb[tid] = 0.f; }
    }
    __syncthreads();

    const int i = it * 256 + tid;
    const bool valid = (i < K);
    const float si = valid ? s_top[i] : 0.f;
    const float wi = valid ? w_top[i] : 0.f;

    float acc = 0.f;
    const float4* sv = (const float4*)sb;
    const float4* wv = (const float4*)wb;
    #pragma unroll 2
    for (int q = 0; q < 26; q++) {
        float4 s4 = sv[q];
        float4 w4 = wv[q];
        acc = fmaf(softplusf(s4.x - si), w4.x, acc);
        acc = fmaf(softplusf(s4.y - si), w4.y, acc);
        acc = fmaf(softplusf(s4.z - si), w4.z, acc);
        acc = fmaf(softplusf(s4.w - si), w4.w, acc);
    }
    float contrib = acc * wi;

    #pragma unroll
    for (int o = 32; o > 0; o >>= 1) contrib += __shfl_down(contrib, o, 64);
    if ((tid & 63) == 0) red2[tid >> 6] = contrib;
    __syncthreads();
    if (tid == 0) {
        float tot = red2[0] + red2[1] + red2[2] + red2[3];
        atomicAdd(&ws[OFF_RNUM + b], tot);
        __threadfence();                      // release our RNUM add
        int v = atomicAdd(&((int*)ws)[OFF_DONE], 1);
        lastflag = (v == PAIR_NBLK - 1);
    }
    __syncthreads();

    if (lastflag && tid < 64) {
        __threadfence();                      // acquire all RNUM adds
        const int t = tid;                    // 0..63 == batch
        float rn  = atomicAdd(&ws[OFF_RNUM + t], 0.0f);  // device-coherent read
        float st  = ws[OFF_SWT + t];
        float sbm = ws[OFF_SWB + t];
        float lr  = rn / (st * sbm + EPSF);

        float wsum = ws[OFF_TWS  + t];
        float pbt  = ws[OFF_TNUM + t] / (wsum + EPSF);
        float vld  = (wsum > 0.f) ? 1.f : 0.f;
        float vtr  = vld * pbt;
        float ps   = ws[OFF_PSUM + t];

        #pragma unroll
        for (int o = 32; o > 0; o >>= 1) {
            lr  += __shfl_down(lr,  o, 64);
            vtr += __shfl_down(vtr, o, 64);
            vld += __shfl_down(vld, o, 64);
            ps  += __shfl_down(ps,  o, 64);
        }
        if (t == 0) {
            float avg_rank  = lr / (float)B;
            float nv        = fmaxf(vld, 1.f);
            float avg_trade = vtr / nv;
            float mean_p    = ps / (float)(B * N);
            out[0] = avg_rank + TRADE_LAMBDA * avg_trade;
            out[1] = avg_rank;
            out[2] = avg_trade;
            out[3] = mean_p;
        }
    }
}

extern "C" void kernel_launch(void* const* d_in, const int* in_sizes, int n_in,
                              void* d_out, int out_size, void* d_ws, size_t ws_size,
                              hipStream_t stream) {
    const float* scores  = (const float*)d_in[0];
    const float* p_trade = (const float*)d_in[1];
    const float* y_rank  = (const float*)d_in[2];
    const float* y_trade = (const float*)d_in[3];
    const float* weights = (const float*)d_in[4];
    const float* mask    = (const float*)d_in[5];
    float* ws  = (float*)d_ws;
    float* out = (float*)d_out;

    hipLaunchKernelGGL(k_select_trade, dim3(128), dim3(1024), 0, stream,
                       scores, p_trade, y_rank, y_trade, weights, mask, ws);
    hipLaunchKernelGGL(k_pair_final, dim3(B, PAIR_IT, PAIR_JZ), dim3(256), 0, stream,
                       ws, out);
}

// Round 5
// 90.807 us; speedup vs baseline: 1.2619x; 1.2619x over previous
//
#include <hip/hip_runtime.h>
#include <math.h>

#define B 64
#define N 4096
#define K 819            // int(4096 * 0.2)
#define NB 128           // histogram bins per row/side
#define EPSF 1e-8f
#define TRADE_LAMBDA 0.25f

// ws layout (floats):
//   htW[B][NB], htC[B][NB], htS[B][NB]   top-set moments (w=sqrt weight):
//       W=sum w, C=sum w*dc, S=sum w*dc^2  (dc = s - bin_center)
//   hbW/hbC/hbS[B][NB]                   bottom-set moments
//   trade_num[B], trade_wsum[B], p_sum[B], smin[B], h[B]
//   rank_acc (1 float), done_counter (1 int)
#define OFF_HTW 0
#define OFF_HTC (B*NB)
#define OFF_HTS (2*B*NB)
#define OFF_HBW (3*B*NB)
#define OFF_HBC (4*B*NB)
#define OFF_HBS (5*B*NB)
#define OFF_TNUM (6*B*NB)
#define OFF_TWS  (6*B*NB + B)
#define OFF_PSUM (6*B*NB + 2*B)
#define OFF_SMIN (6*B*NB + 3*B)
#define OFF_HH   (6*B*NB + 4*B)
#define OFF_RACC (6*B*NB + 5*B)
#define OFF_DONE (6*B*NB + 5*B + 1)

__device__ __forceinline__ unsigned f2key(float f) {
    unsigned u = __float_as_uint(f);
    return (u & 0x80000000u) ? ~u : (u | 0x80000000u);
}

// Scan helpers: wave 0 (scan_top) / wave 1 (scan_bot) find the histogram bin
// containing the rem-th largest/smallest key.
__device__ __forceinline__ void scan_top(const int* h, int rem, int* found) {
    const int t = threadIdx.x;           // 0..63
    const int base = t * 4;
    int c0 = h[base], c1 = h[base+1], c2 = h[base+2], c3 = h[base+3];
    int lane_sum = c0 + c1 + c2 + c3;
    int s = lane_sum;
    #pragma unroll
    for (int o = 1; o < 64; o <<= 1) {
        int v = __shfl_down(s, o, 64);
        if (t + o < 64) s += v;
    }
    int above = s - lane_sum;
    int se3 = above;
    int se2 = se3 + c3;
    int se1 = se2 + c2;
    int se0 = se1 + c1;
    if (se0 < rem && rem <= se0 + c0) { found[0] = base + 0; found[1] = se0; }
    if (se1 < rem && rem <= se1 + c1) { found[0] = base + 1; found[1] = se1; }
    if (se2 < rem && rem <= se2 + c2) { found[0] = base + 2; found[1] = se2; }
    if (se3 < rem && rem <= se3 + c3) { found[0] = base + 3; found[1] = se3; }
}

__device__ __forceinline__ void scan_bot(const int* h, int rem, int* found) {
    const int l = threadIdx.x - 64;      // 0..63 within wave 1
    const int base = l * 4;
    int c0 = h[base], c1 = h[base+1], c2 = h[base+2], c3 = h[base+3];
    int lane_sum = c0 + c1 + c2 + c3;
    int s = lane_sum;
    #pragma unroll
    for (int o = 1; o < 64; o <<= 1) {
        int v = __shfl_up(s, o, 64);
        if (l - o >= 0) s += v;
    }
    int below = s - lane_sum;
    int pe0 = below;
    int pe1 = pe0 + c0;
    int pe2 = pe1 + c1;
    int pe3 = pe2 + c2;
    if (pe0 < rem && rem <= pe0 + c0) { found[0] = base + 0; found[1] = pe0; }
    if (pe1 < rem && rem <= pe1 + c1) { found[0] = base + 1; found[1] = pe1; }
    if (pe2 < rem && rem <= pe2 + c2) { found[0] = base + 2; found[1] = pe2; }
    if (pe3 < rem && rem <= pe3 + c3) { found[0] = base + 3; found[1] = pe3; }
}

// Heterogeneous grid of 128 blocks x 1024 threads:
//   blocks 0..63   : radix-select top-K/bottom-K of y_rank row b, then build
//                    moment-matched score histograms (W, Swdc, Swdc^2) per side
//   blocks 64..127 : trade-loss (BCE) row sums for row b-64
__global__ __launch_bounds__(1024) void k_select_trade(
    const float* __restrict__ scores, const float* __restrict__ p_trade,
    const float* __restrict__ y_rank, const float* __restrict__ y_trade,
    const float* __restrict__ weights, const float* __restrict__ mask,
    float* __restrict__ ws)
{
    __shared__ int histw[16 * 256];   // per-wave slices (radix pass 0), 16 KB
    __shared__ int tot[256];
    __shared__ int hist_t[256];
    __shared__ int hist_b[256];
    __shared__ int found_t[2];
    __shared__ int found_b[2];
    __shared__ float red[48];
    __shared__ int cnts[8];
    __shared__ float htW[NB], htC[NB], htS[NB], hbW[NB], hbC[NB], hbS[NB];

    const int tid = threadIdx.x;

    if (blockIdx.x >= 64) {
        // ================= trade role =================
        const int b = blockIdx.x - 64;
        const float* wt = weights + b * N;
        const float* pt = p_trade + b * N;
        const float* yt = y_trade + b * N;
        const float* mk = mask    + b * N;
        if (b == 0 && tid == 0) {
            ws[OFF_RACC] = 0.f;
            ((int*)ws)[OFF_DONE] = 0;
        }
        float s_wsum = 0.f, s_tnum = 0.f, s_ps = 0.f;
        #pragma unroll
        for (int c = 0; c < 4; c++) {
            int i = tid + c * 1024;
            float p = pt[i], ytr = yt[i], w = wt[i], m = mk[i];
            float mw = w * m;
            float bce = -(ytr * __logf(p) + (1.f - ytr) * __logf(1.f - p));
            s_wsum += mw;
            s_tnum = fmaf(bce, mw, s_tnum);
            s_ps += p;
        }
        #pragma unroll
        for (int o = 32; o > 0; o >>= 1) {
            s_wsum += __shfl_down(s_wsum, o, 64);
            s_tnum += __shfl_down(s_tnum, o, 64);
            s_ps   += __shfl_down(s_ps,   o, 64);
        }
        int wv = tid >> 6;
        if ((tid & 63) == 0) { red[wv] = s_wsum; red[16 + wv] = s_tnum; red[32 + wv] = s_ps; }
        __syncthreads();
        if (tid == 0) {
            float a = 0.f, bb = 0.f, c = 0.f;
            for (int w = 0; w < 16; w++) { a += red[w]; bb += red[16 + w]; c += red[32 + w]; }
            ws[OFF_TWS  + b] = a;
            ws[OFF_TNUM + b] = bb;
            ws[OFF_PSUM + b] = c;
        }
        return;
    }

    // ================= select role =================
    const int b = blockIdx.x;
    const float* yr = y_rank  + b * N;
    const float* sc = scores  + b * N;
    const float* wt = weights + b * N;

    // ---- pass 1: keys + payload into registers, row min/max of scores ----
    unsigned mykeys[4];
    float mysc[4], mysw[4];
    float smn = 1e30f, smx = -1e30f;
    #pragma unroll
    for (int c = 0; c < 4; c++) {
        int i = tid + c * 1024;
        mykeys[c] = f2key(yr[i]);
        mysc[c] = sc[i];
        mysw[c] = sqrtf(wt[i]);
        smn = fminf(smn, mysc[c]);
        smx = fmaxf(smx, mysc[c]);
    }
    #pragma unroll
    for (int o = 32; o > 0; o >>= 1) {
        smn = fminf(smn, __shfl_down(smn, o, 64));
        smx = fmaxf(smx, __shfl_down(smx, o, 64));
    }
    {
        int wv = tid >> 6;
        if ((tid & 63) == 0) { red[wv] = smn; red[16 + wv] = smx; }
    }
    __syncthreads();
    if (tid == 0) {
        float mn = red[0], mx = red[16];
        for (int w = 1; w < 16; w++) { mn = fminf(mn, red[w]); mx = fmaxf(mx, red[16 + w]); }
        red[32] = mn;
        red[33] = fmaxf(mx - mn, 1e-6f) * (1.f / NB);   // bin width h
    }
    __syncthreads();
    const float smin = red[32];
    const float hh = red[33];
    const float invh = 1.f / hh;

    // ---- radix pass 0 (MSB byte): one shared histogram, per-wave slices ----
    for (int i = tid; i < 16 * 256; i += 1024) histw[i] = 0;
    __syncthreads();
    {
        const int slice = (tid >> 6) << 8;
        #pragma unroll
        for (int c = 0; c < 4; c++)
            atomicAdd(&histw[slice | (mykeys[c] >> 24)], 1);
    }
    __syncthreads();
    if (tid < 256) {
        int s = 0;
        #pragma unroll
        for (int w = 0; w < 16; w++) s += histw[(w << 8) | tid];
        tot[tid] = s;
    }
    __syncthreads();
    if (tid < 64)       scan_top(tot, K, found_t);
    else if (tid < 128) scan_bot(tot, K, found_b);
    __syncthreads();

    unsigned pfx_t = ((unsigned)found_t[0]) << 24;
    int rem_t = K - found_t[1];
    unsigned pfx_b = ((unsigned)found_b[0]) << 24;
    int rem_b = K - found_b[1];
    unsigned msk = 0xFF000000u;

    // ---- radix passes 1..3 ----
    #pragma unroll
    for (int pass = 1; pass < 4; pass++) {
        const int shift = 24 - 8 * pass;
        if (tid < 256) hist_t[tid] = 0;
        else if (tid < 512) hist_b[tid - 256] = 0;
        __syncthreads();
        #pragma unroll
        for (int c = 0; c < 4; c++) {
            unsigned kk = mykeys[c];
            if ((kk & msk) == pfx_t) atomicAdd(&hist_t[(kk >> shift) & 0xFF], 1);
            if ((kk & msk) == pfx_b) atomicAdd(&hist_b[(kk >> shift) & 0xFF], 1);
        }
        __syncthreads();
        if (tid < 64)       scan_top(hist_t, rem_t, found_t);
        else if (tid < 128) scan_bot(hist_b, rem_b, found_b);
        __syncthreads();
        pfx_t |= ((unsigned)found_t[0]) << shift;
        rem_t -= found_t[1];
        pfx_b |= ((unsigned)found_b[0]) << shift;
        rem_b -= found_b[1];
        msk |= 0xFFu << shift;
    }
    const unsigned t_top = pfx_t;  // exact K-th largest key
    const unsigned t_bot = pfx_b;  // exact K-th smallest key

    if (tid < 8) cnts[tid] = 0;
    __syncthreads();

    // ---- count strict-side elements ----
    int my_gt = 0, my_lt = 0;
    #pragma unroll
    for (int c = 0; c < 4; c++) {
        unsigned kk = mykeys[c];
        my_gt += (kk > t_top);
        my_lt += (kk < t_bot);
    }
    if (my_gt) atomicAdd(&cnts[0], my_gt);
    if (my_lt) atomicAdd(&cnts[1], my_lt);
    if (tid < NB) {
        htW[tid] = 0.f; htC[tid] = 0.f; htS[tid] = 0.f;
        hbW[tid] = 0.f; hbC[tid] = 0.f; hbS[tid] = 0.f;
    }
    __syncthreads();
    const int c1t = cnts[0];
    const int c1b = cnts[1];

    // ---- moment histograms of included elements (tie-aware quota) ----
    #pragma unroll
    for (int c = 0; c < 4; c++) {
        unsigned kk = mykeys[c];
        bool inc_t = (kk > t_top);
        if (kk == t_top) {
            int tt = atomicAdd(&cnts[2], 1);
            inc_t = (tt < K - c1t);
        }
        if (inc_t) {
            int idx = min(NB - 1, (int)((mysc[c] - smin) * invh));
            float dc = mysc[c] - (smin + (idx + 0.5f) * hh);
            float w = mysw[c];
            atomicAdd(&htW[idx], w);
            atomicAdd(&htC[idx], w * dc);
            atomicAdd(&htS[idx], w * dc * dc);
        }
        bool inc_b = (kk < t_bot);
        if (kk == t_bot) {
            int tt = atomicAdd(&cnts[3], 1);
            inc_b = (tt < K - c1b);
        }
        if (inc_b) {
            int idx = min(NB - 1, (int)((mysc[c] - smin) * invh));
            float dc = mysc[c] - (smin + (idx + 0.5f) * hh);
            float w = mysw[c];
            atomicAdd(&hbW[idx], w);
            atomicAdd(&hbC[idx], w * dc);
            atomicAdd(&hbS[idx], w * dc * dc);
        }
    }
    __syncthreads();
    if (tid < NB) {
        ws[OFF_HTW + b * NB + tid] = htW[tid];
        ws[OFF_HTC + b * NB + tid] = htC[tid];
        ws[OFF_HTS + b * NB + tid] = htS[tid];
        ws[OFF_HBW + b * NB + tid] = hbW[tid];
        ws[OFF_HBC + b * NB + tid] = hbC[tid];
        ws[OFF_HBS + b * NB + tid] = hbS[tid];
    }
    if (tid == 0) {
        ws[OFF_SMIN + b] = smin;
        ws[OFF_HH   + b] = hh;
    }
}

// Rank loss from moment histograms + fused finalize. grid = (B), 256 threads.
// num = sum_ab [ W_a V_b sp(D) + 0.5 sp''(D) (V_b P_a + W_a Q_b) ],
// D = mu_b(bot) - mu_a(top). Second-order moment matching: centroid kills the
// 1st-order term; residual is 3rd-order (~1e-5 rel at h~0.07).
__global__ __launch_bounds__(256) void k_rank(float* __restrict__ ws,
                                              float* __restrict__ out)
{
    __shared__ float W[NB], MU[NB], P[NB];   // top
    __shared__ float V[NB], NU[NB], Q[NB];   // bot
    __shared__ float redk[4];
    __shared__ float sw2[2];
    __shared__ int lastflag;

    const int b = blockIdx.x;
    const int tid = threadIdx.x;
    const float smin = ws[OFF_SMIN + b];
    const float hh   = ws[OFF_HH + b];

    if (tid < NB) {
        float w = ws[OFF_HTW + b * NB + tid];
        float c = ws[OFF_HTC + b * NB + tid];
        float s = ws[OFF_HTS + b * NB + tid];
        float wg = w + 1e-30f;
        W[tid]  = w;
        MU[tid] = smin + (tid + 0.5f) * hh + c / wg;
        P[tid]  = fmaxf(s - c * c / wg, 0.f);
    } else {
        int t = tid - NB;
        float w = ws[OFF_HBW + b * NB + t];
        float c = ws[OFF_HBC + b * NB + t];
        float s = ws[OFF_HBS + b * NB + t];
        float wg = w + 1e-30f;
        V[t]  = w;
        NU[t] = smin + (t + 0.5f) * hh + c / wg;
        Q[t]  = fmaxf(s - c * c / wg, 0.f);
    }
    __syncthreads();

    // exact sqrt-weight sums = sum of bin weights
    if (tid < 64) {
        float s = W[tid] + W[tid + 64];
        #pragma unroll
        for (int o = 32; o > 0; o >>= 1) s += __shfl_down(s, o, 64);
        if (tid == 0) sw2[0] = s;
    } else if (tid < 128) {
        int l = tid - 64;
        float s = V[l] + V[l + 64];
        #pragma unroll
        for (int o = 32; o > 0; o >>= 1) s += __shfl_down(s, o, 64);
        if (l == 0) sw2[1] = s;
    }
    __syncthreads();

    float num = 0.f;
    #pragma unroll 4
    for (int p = 0; p < 64; p++) {
        int idx = (p << 8) + tid;        // 0..16383
        int a = idx >> 7;                // top bin (broadcast per half-wave)
        int j = idx & (NB - 1);          // bot bin (stride-1)
        float wa = W[a], vb = V[j];
        float d = NU[j] - MU[a];         // s_bot - s_top
        float u = __expf(-fabsf(d));
        float sp = fmaxf(d, 0.f) + __logf(1.f + u);
        float r = 1.f / (1.f + u);
        float spp = u * r * r;           // softplus''(d), symmetric in sign
        num += wa * vb * sp + 0.5f * spp * (vb * P[a] + wa * Q[j]);
    }

    #pragma unroll
    for (int o = 32; o > 0; o >>= 1) num += __shfl_down(num, o, 64);
    if ((tid & 63) == 0) redk[tid >> 6] = num;
    __syncthreads();
    if (tid == 0) {
        float tot = redk[0] + redk[1] + redk[2] + redk[3];
        float lrank = tot / (sw2[0] * sw2[1] + EPSF);
        atomicAdd(&ws[OFF_RACC], lrank * (1.f / B));
        __threadfence();
        int v = atomicAdd(&((int*)ws)[OFF_DONE], 1);
        lastflag = (v == B - 1);
    }
    __syncthreads();

    if (lastflag && tid < 64) {
        __threadfence();
        const int t = tid;                 // 0..63 == batch
        float wsum = ws[OFF_TWS  + t];
        float pbt  = ws[OFF_TNUM + t] / (wsum + EPSF);
        float vld  = (wsum > 0.f) ? 1.f : 0.f;
        float vtr  = vld * pbt;
        float ps   = ws[OFF_PSUM + t];
        #pragma unroll
        for (int o = 32; o > 0; o >>= 1) {
            vtr += __shfl_down(vtr, o, 64);
            vld += __shfl_down(vld, o, 64);
            ps  += __shfl_down(ps,  o, 64);
        }
        if (t == 0) {
            float avg_rank  = atomicAdd(&ws[OFF_RACC], 0.0f);  // coherent read
            float nv        = fmaxf(vld, 1.f);
            float avg_trade = vtr / nv;
            float mean_p    = ps / (float)(B * N);
            out[0] = avg_rank + TRADE_LAMBDA * avg_trade;
            out[1] = avg_rank;
            out[2] = avg_trade;
            out[3] = mean_p;
        }
    }
}

extern "C" void kernel_launch(void* const* d_in, const int* in_sizes, int n_in,
                              void* d_out, int out_size, void* d_ws, size_t ws_size,
                              hipStream_t stream) {
    const float* scores  = (const float*)d_in[0];
    const float* p_trade = (const float*)d_in[1];
    const float* y_rank  = (const float*)d_in[2];
    const float* y_trade = (const float*)d_in[3];
    const float* weights = (const float*)d_in[4];
    const float* mask    = (const float*)d_in[5];
    float* ws  = (float*)d_ws;
    float* out = (float*)d_out;

    hipLaunchKernelGGL(k_select_trade, dim3(128), dim3(1024), 0, stream,
                       scores, p_trade, y_rank, y_trade, weights, mask, ws);
    hipLaunchKernelGGL(k_rank, dim3(B), dim3(256), 0, stream, ws, out);
}

// Round 6
// 87.041 us; speedup vs baseline: 1.3165x; 1.0433x over previous
//
#include <hip/hip_runtime.h>
#include <math.h>

#define B 64
#define N 4096
#define K 819            // int(4096 * 0.2)
#define NB 128           // score-histogram bins per row/side
#define EPSF 1e-8f
#define TRADE_LAMBDA 0.25f

// ws layout (floats): rank[B] @0, trade_wsum[B] @64, trade_num[B] @128, p_sum[B] @192
#define OFF_RANK 0
#define OFF_TWS  B
#define OFF_TNUM (2*B)
#define OFF_PSUM (3*B)

__device__ __forceinline__ unsigned f2key(float f) {
    unsigned u = __float_as_uint(f);
    return (u & 0x80000000u) ? ~u : (u | 0x80000000u);
}

// Scan helpers: wave 0 (scan_top) / wave 1 (scan_bot) find the histogram bin
// containing the rem-th largest/smallest key.
__device__ __forceinline__ void scan_top(const int* h, int rem, int* found) {
    const int t = threadIdx.x;           // 0..63
    const int base = t * 4;
    int c0 = h[base], c1 = h[base+1], c2 = h[base+2], c3 = h[base+3];
    int lane_sum = c0 + c1 + c2 + c3;
    int s = lane_sum;
    #pragma unroll
    for (int o = 1; o < 64; o <<= 1) {
        int v = __shfl_down(s, o, 64);
        if (t + o < 64) s += v;
    }
    int above = s - lane_sum;
    int se3 = above;
    int se2 = se3 + c3;
    int se1 = se2 + c2;
    int se0 = se1 + c1;
    if (se0 < rem && rem <= se0 + c0) { found[0] = base + 0; found[1] = se0; }
    if (se1 < rem && rem <= se1 + c1) { found[0] = base + 1; found[1] = se1; }
    if (se2 < rem && rem <= se2 + c2) { found[0] = base + 2; found[1] = se2; }
    if (se3 < rem && rem <= se3 + c3) { found[0] = base + 3; found[1] = se3; }
}

__device__ __forceinline__ void scan_bot(const int* h, int rem, int* found) {
    const int l = threadIdx.x - 64;      // 0..63 within wave 1
    const int base = l * 4;
    int c0 = h[base], c1 = h[base+1], c2 = h[base+2], c3 = h[base+3];
    int lane_sum = c0 + c1 + c2 + c3;
    int s = lane_sum;
    #pragma unroll
    for (int o = 1; o < 64; o <<= 1) {
        int v = __shfl_up(s, o, 64);
        if (l - o >= 0) s += v;
    }
    int below = s - lane_sum;
    int pe0 = below;
    int pe1 = pe0 + c0;
    int pe2 = pe1 + c1;
    int pe3 = pe2 + c2;
    if (pe0 < rem && rem <= pe0 + c0) { found[0] = base + 0; found[1] = pe0; }
    if (pe1 < rem && rem <= pe1 + c1) { found[0] = base + 1; found[1] = pe1; }
    if (pe2 < rem && rem <= pe2 + c2) { found[0] = base + 2; found[1] = pe2; }
    if (pe3 < rem && rem <= pe3 + c3) { found[0] = base + 3; found[1] = pe3; }
}

// Heterogeneous grid of 128 blocks x 1024 threads:
//   blocks 0..63   : radix-select top-K/bottom-K of y_rank row b, build
//                    moment-matched score histograms in LDS, and compute the
//                    row's rank loss INLINE (no ws round-trip, no 2nd kernel)
//   blocks 64..127 : trade-loss (BCE) row sums for row b-64
__global__ __launch_bounds__(1024) void k_fused(
    const float* __restrict__ scores, const float* __restrict__ p_trade,
    const float* __restrict__ y_rank, const float* __restrict__ y_trade,
    const float* __restrict__ weights, const float* __restrict__ mask,
    float* __restrict__ ws)
{
    __shared__ int histw[16 * 256];   // per-wave slices (radix pass 0), 16 KB
    __shared__ int tot[256];
    __shared__ int hist_t[256];
    __shared__ int hist_b[256];
    __shared__ int found_t[2];
    __shared__ int found_b[2];
    __shared__ float red[48];
    __shared__ int cnts[8];
    // top moments: W / C->MU / S->P ; bottom: V / C->NU / S->Q (converted in place)
    __shared__ float htW[NB], htC[NB], htS[NB], hbW[NB], hbC[NB], hbS[NB];

    const int tid = threadIdx.x;

    if (blockIdx.x >= 64) {
        // ================= trade role =================
        const int b = blockIdx.x - 64;
        const float* wt = weights + b * N;
        const float* pt = p_trade + b * N;
        const float* yt = y_trade + b * N;
        const float* mk = mask    + b * N;
        float s_wsum = 0.f, s_tnum = 0.f, s_ps = 0.f;
        #pragma unroll
        for (int c = 0; c < 4; c++) {
            int i = tid + c * 1024;
            float p = pt[i], ytr = yt[i], w = wt[i], m = mk[i];
            float mw = w * m;
            float bce = -(ytr * __logf(p) + (1.f - ytr) * __logf(1.f - p));
            s_wsum += mw;
            s_tnum = fmaf(bce, mw, s_tnum);
            s_ps += p;
        }
        #pragma unroll
        for (int o = 32; o > 0; o >>= 1) {
            s_wsum += __shfl_down(s_wsum, o, 64);
            s_tnum += __shfl_down(s_tnum, o, 64);
            s_ps   += __shfl_down(s_ps,   o, 64);
        }
        int wv = tid >> 6;
        if ((tid & 63) == 0) { red[wv] = s_wsum; red[16 + wv] = s_tnum; red[32 + wv] = s_ps; }
        __syncthreads();
        if (tid == 0) {
            float a = 0.f, bb = 0.f, c = 0.f;
            for (int w = 0; w < 16; w++) { a += red[w]; bb += red[16 + w]; c += red[32 + w]; }
            ws[OFF_TWS  + b] = a;
            ws[OFF_TNUM + b] = bb;
            ws[OFF_PSUM + b] = c;
        }
        return;
    }

    // ================= select + rank role =================
    const int b = blockIdx.x;
    const float* yr = y_rank  + b * N;
    const float* sc = scores  + b * N;
    const float* wt = weights + b * N;

    // ---- keys + payload into registers, row min/max of scores ----
    unsigned mykeys[4];
    float mysc[4], mysw[4];
    float smn = 1e30f, smx = -1e30f;
    #pragma unroll
    for (int c = 0; c < 4; c++) {
        int i = tid + c * 1024;
        mykeys[c] = f2key(yr[i]);
        mysc[c] = sc[i];
        mysw[c] = sqrtf(wt[i]);
        smn = fminf(smn, mysc[c]);
        smx = fmaxf(smx, mysc[c]);
    }
    #pragma unroll
    for (int o = 32; o > 0; o >>= 1) {
        smn = fminf(smn, __shfl_down(smn, o, 64));
        smx = fmaxf(smx, __shfl_down(smx, o, 64));
    }
    {
        int wv = tid >> 6;
        if ((tid & 63) == 0) { red[wv] = smn; red[16 + wv] = smx; }
    }
    __syncthreads();
    if (tid == 0) {
        float mn = red[0], mx = red[16];
        for (int w = 1; w < 16; w++) { mn = fminf(mn, red[w]); mx = fmaxf(mx, red[16 + w]); }
        red[32] = mn;
        red[33] = fmaxf(mx - mn, 1e-6f) * (1.f / NB);   // bin width h
    }
    __syncthreads();
    const float smin = red[32];
    const float hh = red[33];
    const float invh = 1.f / hh;

    // ---- radix pass 0 (MSB byte): one shared histogram, per-wave slices ----
    for (int i = tid; i < 16 * 256; i += 1024) histw[i] = 0;
    __syncthreads();
    {
        const int slice = (tid >> 6) << 8;
        #pragma unroll
        for (int c = 0; c < 4; c++)
            atomicAdd(&histw[slice | (mykeys[c] >> 24)], 1);
    }
    __syncthreads();
    if (tid < 256) {
        int s = 0;
        #pragma unroll
        for (int w = 0; w < 16; w++) s += histw[(w << 8) | tid];
        tot[tid] = s;
    }
    __syncthreads();
    if (tid < 64)       scan_top(tot, K, found_t);
    else if (tid < 128) scan_bot(tot, K, found_b);
    __syncthreads();

    unsigned pfx_t = ((unsigned)found_t[0]) << 24;
    int rem_t = K - found_t[1];
    unsigned pfx_b = ((unsigned)found_b[0]) << 24;
    int rem_b = K - found_b[1];
    unsigned msk = 0xFF000000u;

    // ---- radix passes 1..3 (few candidates, mantissa-uniform) ----
    #pragma unroll
    for (int pass = 1; pass < 4; pass++) {
        const int shift = 24 - 8 * pass;
        if (tid < 256) hist_t[tid] = 0;
        else if (tid < 512) hist_b[tid - 256] = 0;
        __syncthreads();
        #pragma unroll
        for (int c = 0; c < 4; c++) {
            unsigned kk = mykeys[c];
            if ((kk & msk) == pfx_t) atomicAdd(&hist_t[(kk >> shift) & 0xFF], 1);
            if ((kk & msk) == pfx_b) atomicAdd(&hist_b[(kk >> shift) & 0xFF], 1);
        }
        __syncthreads();
        if (tid < 64)       scan_top(hist_t, rem_t, found_t);
        else if (tid < 128) scan_bot(hist_b, rem_b, found_b);
        __syncthreads();
        pfx_t |= ((unsigned)found_t[0]) << shift;
        rem_t -= found_t[1];
        pfx_b |= ((unsigned)found_b[0]) << shift;
        rem_b -= found_b[1];
        msk |= 0xFFu << shift;
    }
    const unsigned t_top = pfx_t;  // exact K-th largest key
    const unsigned t_bot = pfx_b;  // exact K-th smallest key

    if (tid < 8) cnts[tid] = 0;
    __syncthreads();

    // ---- count strict-side elements ----
    int my_gt = 0, my_lt = 0;
    #pragma unroll
    for (int c = 0; c < 4; c++) {
        unsigned kk = mykeys[c];
        my_gt += (kk > t_top);
        my_lt += (kk < t_bot);
    }
    if (my_gt) atomicAdd(&cnts[0], my_gt);
    if (my_lt) atomicAdd(&cnts[1], my_lt);
    if (tid < NB) {
        htW[tid] = 0.f; htC[tid] = 0.f; htS[tid] = 0.f;
        hbW[tid] = 0.f; hbC[tid] = 0.f; hbS[tid] = 0.f;
    }
    __syncthreads();
    const int c1t = cnts[0];
    const int c1b = cnts[1];

    // ---- moment histograms of included elements (tie-aware quota) ----
    #pragma unroll
    for (int c = 0; c < 4; c++) {
        unsigned kk = mykeys[c];
        bool inc_t = (kk > t_top);
        if (kk == t_top) {
            int tt = atomicAdd(&cnts[2], 1);
            inc_t = (tt < K - c1t);
        }
        if (inc_t) {
            int idx = min(NB - 1, (int)((mysc[c] - smin) * invh));
            float dc = mysc[c] - (smin + (idx + 0.5f) * hh);
            float w = mysw[c];
            atomicAdd(&htW[idx], w);
            atomicAdd(&htC[idx], w * dc);
            atomicAdd(&htS[idx], w * dc * dc);
        }
        bool inc_b = (kk < t_bot);
        if (kk == t_bot) {
            int tt = atomicAdd(&cnts[3], 1);
            inc_b = (tt < K - c1b);
        }
        if (inc_b) {
            int idx = min(NB - 1, (int)((mysc[c] - smin) * invh));
            float dc = mysc[c] - (smin + (idx + 0.5f) * hh);
            float w = mysw[c];
            atomicAdd(&hbW[idx], w);
            atomicAdd(&hbC[idx], w * dc);
            atomicAdd(&hbS[idx], w * dc * dc);
        }
    }
    __syncthreads();

    // ---- convert raw moments to (W, MU, P) / (V, NU, Q) in place ----
    if (tid < NB) {
        float w = htW[tid], c = htC[tid], s = htS[tid];
        float wg = w + 1e-30f;
        htC[tid] = smin + (tid + 0.5f) * hh + c / wg;        // MU
        htS[tid] = fmaxf(s - c * c / wg, 0.f);               // P (central 2nd moment * w)
    } else if (tid < 2 * NB) {
        int t = tid - NB;
        float w = hbW[t], c = hbC[t], s = hbS[t];
        float wg = w + 1e-30f;
        hbC[t] = smin + (t + 0.5f) * hh + c / wg;            // NU
        hbS[t] = fmaxf(s - c * c / wg, 0.f);                 // Q
    }
    __syncthreads();

    // exact sqrt-weight sums (denominator factorizes)
    if (tid < 64) {
        float s = htW[tid] + htW[tid + 64];
        #pragma unroll
        for (int o = 32; o > 0; o >>= 1) s += __shfl_down(s, o, 64);
        if (tid == 0) red[40] = s;
    } else if (tid < 128) {
        int l = tid - 64;
        float s = hbW[l] + hbW[l + 64];
        #pragma unroll
        for (int o = 32; o > 0; o >>= 1) s += __shfl_down(s, o, 64);
        if (l == 0) red[41] = s;
    }

    // ---- rank pair loop: 16384 bin pairs, 16 per thread ----
    // num = sum_ab [ W_a V_b sp(D) + 0.5 sp''(D) (V_b P_a + W_a Q_b) ],
    // D = NU_b - MU_a. Centroid kills 1st-order term; residual ~3rd order.
    float num = 0.f;
    #pragma unroll
    for (int p = 0; p < 16; p++) {
        int idx = (p << 10) + tid;       // 0..16383
        int a = idx >> 7;                // top bin (broadcast per 128 lanes)
        int j = idx & (NB - 1);          // bot bin (stride-1, conflict-free)
        float wa = htW[a], vb = hbW[j];
        float d = hbC[j] - htC[a];       // s_bot - s_top
        float u = __expf(-fabsf(d));
        float sp = fmaxf(d, 0.f) + __logf(1.f + u);
        float r = 1.f / (1.f + u);
        float spp = u * r * r;           // softplus''(d), symmetric in sign
        num += wa * vb * sp + 0.5f * spp * (vb * htS[a] + wa * hbS[j]);
    }
    #pragma unroll
    for (int o = 32; o > 0; o >>= 1) num += __shfl_down(num, o, 64);
    {
        int wv = tid >> 6;
        if ((tid & 63) == 0) red[wv] = num;
    }
    __syncthreads();
    if (tid == 0) {
        float tot2 = 0.f;
        for (int w = 0; w < 16; w++) tot2 += red[w];
        ws[OFF_RANK + b] = tot2 / (red[40] * red[41] + EPSF);
    }
}

// Finalize: one wave, all 64 batches. Kernel boundary = full coherence.
__global__ __launch_bounds__(64) void k_fin(const float* __restrict__ ws,
                                            float* __restrict__ out)
{
    const int t = threadIdx.x;  // 0..63 == batch
    float lr   = ws[OFF_RANK + t];
    float wsum = ws[OFF_TWS  + t];
    float pbt  = ws[OFF_TNUM + t] / (wsum + EPSF);
    float vld  = (wsum > 0.f) ? 1.f : 0.f;
    float vtr  = vld * pbt;
    float ps   = ws[OFF_PSUM + t];

    #pragma unroll
    for (int o = 32; o > 0; o >>= 1) {
        lr  += __shfl_down(lr,  o, 64);
        vtr += __shfl_down(vtr, o, 64);
        vld += __shfl_down(vld, o, 64);
        ps  += __shfl_down(ps,  o, 64);
    }
    if (t == 0) {
        float avg_rank  = lr / (float)B;
        float nv        = fmaxf(vld, 1.f);
        float avg_trade = vtr / nv;
        float mean_p    = ps / (float)(B * N);
        out[0] = avg_rank + TRADE_LAMBDA * avg_trade;
        out[1] = avg_rank;
        out[2] = avg_trade;
        out[3] = mean_p;
    }
}

extern "C" void kernel_launch(void* const* d_in, const int* in_sizes, int n_in,
                              void* d_out, int out_size, void* d_ws, size_t ws_size,
                              hipStream_t stream) {
    const float* scores  = (const float*)d_in[0];
    const float* p_trade = (const float*)d_in[1];
    const float* y_rank  = (const float*)d_in[2];
    const float* y_trade = (const float*)d_in[3];
    const float* weights = (const float*)d_in[4];
    const float* mask    = (const float*)d_in[5];
    float* ws  = (float*)d_ws;
    float* out = (float*)d_out;

    hipLaunchKernelGGL(k_fused, dim3(128), dim3(1024), 0, stream,
                       scores, p_trade, y_rank, y_trade, weights, mask, ws);
    hipLaunchKernelGGL(k_fin, dim3(1), dim3(64), 0, stream, ws, out);
}